// Round 13
// baseline (236.227 us; speedup 1.0000x reference)
//
#include <hip/hip_runtime.h>
#include <math.h>

#define NSAMP 262144
#define TMS 32   // samples per block in k1 (32 -> halves accumulator regs)

typedef __bf16  bf16x8 __attribute__((ext_vector_type(8)));
typedef __bf16  bf16x4 __attribute__((ext_vector_type(4)));
typedef float   f32x4  __attribute__((ext_vector_type(4)));

// tanh via native exp + native rcp (1-ulp). Verified round 9: -68 us.
__device__ __forceinline__ float fast_tanh(float v) {
  float e = __expf(2.0f * v);
  return 1.0f - 2.0f * __builtin_amdgcn_rcpf(e + 1.0f);
}
__device__ __forceinline__ unsigned short f2bf(float f) {
  unsigned u = __float_as_uint(f);
  unsigned r = (u + 0x7FFFu + ((u >> 16) & 1u)) >> 16;   // RNE
  return (unsigned short)r;
}

// ---------------------------------------------------------------------------
// K0: pack all weights into bf16 MFMA *A-operand* fragments of W^T:
// lane l holds W[k = ks*32+(l>>4)*8+i][n = nt*16+(l&15)], zero-padded OOB.
// sections: L1 [0,128) NKS=4 N=512 | L2 [128,384) NKS=16 N=256
//   L3 [384,416) NKS=8 N=64 | E1 [416,432) NKS=4 N=64
//   E0 [432,440) NKS=1 N=128 K=8 | L4 [440,442) NKS=2 N=8->16 K=64
//   E2 [442,444) NKS=2 N=16 K=64
// ---------------------------------------------------------------------------
__global__ void k0_pack(const float* __restrict__ W0, const float* __restrict__ W1,
                        const float* __restrict__ W2, const float* __restrict__ E1w,
                        const float* __restrict__ E0w, const float* __restrict__ W3,
                        const float* __restrict__ E2w,
                        unsigned short* __restrict__ wpack)
{
  const int f = blockIdx.x;
  const int lane = threadIdx.x;
  const float* W; int NKS, N, Kreal, Nreal, local;
  if (f < 128)      { W = W0;  NKS = 4;  N = 512; Kreal = 128; Nreal = 512; local = f; }
  else if (f < 384) { W = W1;  NKS = 16; N = 256; Kreal = 512; Nreal = 256; local = f - 128; }
  else if (f < 416) { W = W2;  NKS = 8;  N = 64;  Kreal = 256; Nreal = 64;  local = f - 384; }
  else if (f < 432) { W = E1w; NKS = 4;  N = 64;  Kreal = 128; Nreal = 64;  local = f - 416; }
  else if (f < 440) { W = E0w; NKS = 1;  N = 128; Kreal = 8;   Nreal = 128; local = f - 432; }
  else if (f < 442) { W = W3;  NKS = 2;  N = 8;   Kreal = 64;  Nreal = 8;   local = f - 440; }
  else              { W = E2w; NKS = 2;  N = 16;  Kreal = 64;  Nreal = 16;  local = f - 442; }
  const int nt = local / NKS, ks = local % NKS;
  const int n = nt * 16 + (lane & 15);
  const int kbase = ks * 32 + (lane >> 4) * 8;
  unsigned short* out = wpack + ((size_t)f * 64 + lane) * 8;
#pragma unroll
  for (int i = 0; i < 8; ++i) {
    const int k = kbase + i;
    const float v = (k < Kreal && n < Nreal) ? W[(size_t)k * N + n] : 0.f;
    out[i] = f2bf(v);
  }
}

// ---------------------------------------------------------------------------
// Swapped-operand layer, NKS=4, 2 sample groups; a-frags cached across tiles.
// ---------------------------------------------------------------------------
template<int NTPW>
__device__ __forceinline__ void layer_nks4(
    const char* __restrict__ in, int inRowB, char* __restrict__ outb, int outRowB,
    const unsigned short* __restrict__ wp, int fragBase,
    const float* __restrict__ bias, int lane, int wv)
{
  const int l15 = lane & 15, lg = lane >> 4;
  const int sw = (l15 & 7) << 4;
  bf16x8 a[2][4];
#pragma unroll
  for (int sg = 0; sg < 2; ++sg)
#pragma unroll
    for (int q = 0; q < 4; ++q)
      a[sg][q] = *(const bf16x8*)(in + (sg * 16 + l15) * inRowB + ((q * 64 + lg * 16) ^ sw));
#pragma unroll
  for (int t = 0; t < NTPW; ++t) {
    const int nt = wv * NTPW + t;
    const float4 bv = *(const float4*)(bias + nt * 16 + lg * 4);
    f32x4 acc[2];
#pragma unroll
    for (int sg = 0; sg < 2; ++sg) acc[sg] = {bv.x, bv.y, bv.z, bv.w};
#pragma unroll
    for (int q = 0; q < 4; ++q) {
      const bf16x8 w = *(const bf16x8*)(wp + ((size_t)(fragBase + nt * 4 + q) * 64 + lane) * 8);
#pragma unroll
      for (int sg = 0; sg < 2; ++sg)
        acc[sg] = __builtin_amdgcn_mfma_f32_16x16x32_bf16(w, a[sg][q], acc[sg], 0, 0, 0);
    }
#pragma unroll
    for (int sg = 0; sg < 2; ++sg) {
      bf16x4 tv;
#pragma unroll
      for (int r = 0; r < 4; ++r) tv[r] = (__bf16)fast_tanh(acc[sg][r]);
      *(bf16x4*)(outb + (sg * 16 + l15) * outRowB + ((nt * 32 + lg * 8) ^ sw)) = tv;
    }
  }
}

// ---------------------------------------------------------------------------
// L2 quarter-accumulation: 4 kfrags (128 feats) from H1 (rows 256B) into
// persistent acc[4 tiles][2 sg]. ksOff = pass*4 within L2's 16 kfrags.
// ---------------------------------------------------------------------------
__device__ __forceinline__ void l2_accum_q(
    const char* __restrict__ H1, const unsigned short* __restrict__ wp,
    int ksOff, f32x4 (&acc)[4][2], int lane, int wv)
{
  const int l15 = lane & 15, lg = lane >> 4;
  const int sw = (l15 & 7) << 4;
  bf16x8 a[2][4];
#pragma unroll
  for (int sg = 0; sg < 2; ++sg)
#pragma unroll
    for (int q = 0; q < 4; ++q)
      a[sg][q] = *(const bf16x8*)(H1 + (sg * 16 + l15) * 256 + ((q * 64 + lg * 16) ^ sw));
#pragma unroll
  for (int t = 0; t < 4; ++t) {
    const int nt = wv * 4 + t;
#pragma unroll
    for (int q = 0; q < 4; ++q) {
      const bf16x8 w = *(const bf16x8*)(wp + ((size_t)(128 + nt * 16 + ksOff + q) * 64 + lane) * 8);
#pragma unroll
      for (int sg = 0; sg < 2; ++sg)
        acc[t][sg] = __builtin_amdgcn_mfma_f32_16x16x32_bf16(w, a[sg][q], acc[t][sg], 0, 0, 0);
    }
  }
}

// ---------------------------------------------------------------------------
// K1: fused MLP, TMS=32, 32 KB LDS. Total regs/thread ~= arch(~90) +
// accum(acc2 32 + acc3 8) ~= 130 -> 3-4 waves/SIMD (vs 2 at TMS=64's 184).
//  X  [0,8K): x tile; reused: L3o(4K) + zb(0.5K)
//  H1 [8K,16K): L1 quarter out; reused: E0out
//  H2 [16K,32K): L2 out (rows 512B); reused: e1(4K)
// ---------------------------------------------------------------------------
__global__ __launch_bounds__(256, 2) void k1_mfma(
    const float* __restrict__ x, const unsigned short* __restrict__ wpack,
    const float* __restrict__ b0, const float* __restrict__ b1,
    const float* __restrict__ b2, const float* __restrict__ b3,
    const float* __restrict__ eb0, const float* __restrict__ eb1,
    const float* __restrict__ eb2,
    float* __restrict__ zg, float* __restrict__ gamma)
{
  __shared__ char sm[32768];
  char* X   = sm;                    // 8 KB, rows 256B
  char* H1  = sm + 8192;             // 8 KB, rows 256B
  char* H2  = sm + 16384;            // 16 KB, rows 512B
  char* L3o = sm;                    // 4 KB, rows 128B (after X dead)
  char* zb  = sm + 4096;             // [32][16B] bf16 z, 0.5 KB
  char* E0o = sm + 8192;             // 8 KB, rows 256B (after H1 dead)
  char* e1  = sm + 16384;            // 4 KB, rows 128B (after H2 dead)

  const int tid = threadIdx.x;
  const int lane = tid & 63, wv = tid >> 6;
  const int l15 = lane & 15, lg = lane >> 4;
  const int sw = (l15 & 7) << 4;
  const int blk = blockIdx.x;

  // ---- stage x -> X: bf16 [32][128], swizzled ----
  {
    const float* xb = x + (size_t)blk * (TMS * 128);
#pragma unroll
    for (int p = 0; p < 4; ++p) {
      const int v = tid + p * 256;
      const float4 t = *(const float4*)(xb + v * 4);
      const int s = v >> 5, k0 = (v & 31) * 4;
      bf16x4 h = {(__bf16)t.x, (__bf16)t.y, (__bf16)t.z, (__bf16)t.w};
      *(bf16x4*)(X + s * 256 + ((k0 * 2) ^ ((s & 7) << 4))) = h;
    }
  }

  // L2 persistent accumulators, bias-initialized: 4 n-tiles x 2 sg
  f32x4 acc2[4][2];
#pragma unroll
  for (int t = 0; t < 4; ++t) {
    const float4 bv = *(const float4*)(b1 + (wv * 4 + t) * 16 + lg * 4);
#pragma unroll
    for (int sg = 0; sg < 2; ++sg) acc2[t][sg] = {bv.x, bv.y, bv.z, bv.w};
  }
  __syncthreads();

  // ---- L1/L2 quarter passes: L1 n-quarter (8 tiles, 2/wave) -> H1 -> L2 k-quarter ----
#pragma unroll
  for (int p = 0; p < 4; ++p) {
    layer_nks4<2>(X, 256, H1, 256, wpack, p * 32, b0 + p * 128, lane, wv);
    __syncthreads();
    l2_accum_q(H1, wpack, p * 4, acc2, lane, wv);
    __syncthreads();
  }

  // ---- L2 epilogue -> H2 (rows 512B; all 16 n-tiles) ----
#pragma unroll
  for (int t = 0; t < 4; ++t)
#pragma unroll
    for (int sg = 0; sg < 2; ++sg) {
      bf16x4 tv;
#pragma unroll
      for (int r = 0; r < 4; ++r) tv[r] = (__bf16)fast_tanh(acc2[t][sg][r]);
      *(bf16x4*)(H2 + (sg * 16 + l15) * 512 + (((wv * 4 + t) * 32 + lg * 8) ^ sw)) = tv;
    }
  __syncthreads();

  // ---- L3: 256 -> 64 tanh; nt = wv (4 tiles) ----
  {
    f32x4 acc3[2];
    const float4 bv = *(const float4*)(b2 + wv * 16 + lg * 4);
#pragma unroll
    for (int sg = 0; sg < 2; ++sg) acc3[sg] = {bv.x, bv.y, bv.z, bv.w};
#pragma unroll
    for (int q = 0; q < 8; ++q) {
      const bf16x8 w = *(const bf16x8*)(wpack + ((size_t)(384 + wv * 8 + q) * 64 + lane) * 8);
#pragma unroll
      for (int sg = 0; sg < 2; ++sg) {
        const bf16x8 a = *(const bf16x8*)(H2 + (sg * 16 + l15) * 512 + ((q * 64 + lg * 16) ^ sw));
        acc3[sg] = __builtin_amdgcn_mfma_f32_16x16x32_bf16(w, a, acc3[sg], 0, 0, 0);
      }
    }
#pragma unroll
    for (int sg = 0; sg < 2; ++sg) {
      bf16x4 tv;
#pragma unroll
      for (int r = 0; r < 4; ++r) tv[r] = (__bf16)fast_tanh(acc3[sg][r]);
      *(bf16x4*)(L3o + (sg * 16 + l15) * 128 + ((wv * 32 + lg * 8) ^ sw)) = tv;
    }
  }
  __syncthreads();

  // ---- L4: 64 -> 8 (N padded 16); waves 0,1 handle sg 0,1 ----
  if (wv < 2) {
    bf16x8 a[2];
#pragma unroll
    for (int q = 0; q < 2; ++q)
      a[q] = *(const bf16x8*)(L3o + (wv * 16 + l15) * 128 + ((q * 64 + lg * 16) ^ sw));
    float4 bv = {0.f, 0.f, 0.f, 0.f};
    if (lg < 2) bv = *(const float4*)(b3 + lg * 4);
    f32x4 acc = {bv.x, bv.y, bv.z, bv.w};
#pragma unroll
    for (int q = 0; q < 2; ++q) {
      const bf16x8 w = *(const bf16x8*)(wpack + ((size_t)(440 + q) * 64 + lane) * 8);
      acc = __builtin_amdgcn_mfma_f32_16x16x32_bf16(w, a[q], acc, 0, 0, 0);
    }
    if (lg < 2) {
      *(f32x4*)(zg + ((size_t)blk * 32 + wv * 16 + l15) * 8 + lg * 4) = acc;
      bf16x4 zv;
#pragma unroll
      for (int r = 0; r < 4; ++r) zv[r] = (__bf16)acc[r];
      *(bf16x4*)(zb + (wv * 16 + l15) * 16 + lg * 8) = zv;
    }
  }
  __syncthreads();

  // ---- E0: 8 -> 128 tanh (K padded to 32, zero weights kill k>=8); 2 tiles/wave ----
  {
    bf16x8 az[2];
#pragma unroll
    for (int sg = 0; sg < 2; ++sg)
      az[sg] = *(const bf16x8*)(zb + (sg * 16 + l15) * 16);
#pragma unroll
    for (int t = 0; t < 2; ++t) {
      const int nt = wv * 2 + t;
      const float4 bv = *(const float4*)(eb0 + nt * 16 + lg * 4);
      const bf16x8 w = *(const bf16x8*)(wpack + ((size_t)(432 + nt) * 64 + lane) * 8);
#pragma unroll
      for (int sg = 0; sg < 2; ++sg) {
        f32x4 acc = {bv.x, bv.y, bv.z, bv.w};
        acc = __builtin_amdgcn_mfma_f32_16x16x32_bf16(w, az[sg], acc, 0, 0, 0);
        bf16x4 tv;
#pragma unroll
        for (int r = 0; r < 4; ++r) tv[r] = (__bf16)fast_tanh(acc[r]);
        *(bf16x4*)(E0o + (sg * 16 + l15) * 256 + ((nt * 32 + lg * 8) ^ sw)) = tv;
      }
    }
  }
  __syncthreads();

  layer_nks4<1>(E0o, 256, e1, 128, wpack, 416, eb1, lane, wv);    // E1 (4 tiles)
  __syncthreads();

  // ---- E2 + softmax; waves 0,1 handle sg 0,1 ----
  if (wv < 2) {
    bf16x8 a[2];
#pragma unroll
    for (int q = 0; q < 2; ++q)
      a[q] = *(const bf16x8*)(e1 + (wv * 16 + l15) * 128 + ((q * 64 + lg * 16) ^ sw));
    const float4 bv = *(const float4*)(eb2 + lg * 4);
    f32x4 acc = {bv.x, bv.y, bv.z, bv.w};
#pragma unroll
    for (int q = 0; q < 2; ++q) {
      const bf16x8 w = *(const bf16x8*)(wpack + ((size_t)(442 + q) * 64 + lane) * 8);
      acc = __builtin_amdgcn_mfma_f32_16x16x32_bf16(w, a[q], acc, 0, 0, 0);
    }
    float m = fmaxf(fmaxf(acc[0], acc[1]), fmaxf(acc[2], acc[3]));
    m = fmaxf(m, __shfl_xor(m, 16));
    m = fmaxf(m, __shfl_xor(m, 32));
    float e0v = __expf(acc[0] - m), e1v = __expf(acc[1] - m);
    float e2v = __expf(acc[2] - m), e3v = __expf(acc[3] - m);
    float s = e0v + e1v + e2v + e3v;
    s += __shfl_xor(s, 16);
    s += __shfl_xor(s, 32);
    const float inv = __builtin_amdgcn_rcpf(s);
    float4 g = {e0v * inv, e1v * inv, e2v * inv, e3v * inv};
    *(float4*)(gamma + ((size_t)blk * 32 + wv * 16 + l15) * 16 + lg * 4) = g;
  }
}

// ---------------------------------------------------------------------------
// K2a: moment partials. 1024 blocks x 256 samples each, LDS-staged.
// ---------------------------------------------------------------------------
__global__ __launch_bounds__(256) void k2a_partial(
    const float* __restrict__ zg, const float* __restrict__ gamma,
    float* __restrict__ part)
{
  __shared__ float zl[256 * 8];
  __shared__ float gl[256 * 16];
  __shared__ float red[4][16][46];
  const int tid = threadIdx.x;
  const int blk = blockIdx.x;
  const int s0 = blk * 256;

  {
    const float4 a = *(const float4*)(zg + (size_t)(s0 + tid) * 8);
    const float4 b = *(const float4*)(zg + (size_t)(s0 + tid) * 8 + 4);
    *(float4*)(&zl[tid * 8])     = a;
    *(float4*)(&zl[tid * 8 + 4]) = b;
  }
  {
    const float* gp = gamma + (size_t)(s0 + tid) * 16;
#pragma unroll
    for (int q = 0; q < 4; ++q)
      *(float4*)(&gl[tid * 16 + q * 4]) = *(const float4*)(gp + q * 4);
  }
  __syncthreads();

  const int k = tid & 15, sub = tid >> 4;
  float m2[36], m1[8], gs = 0.f;
#pragma unroll
  for (int i = 0; i < 36; ++i) m2[i] = 0.f;
#pragma unroll
  for (int i = 0; i < 8; ++i) m1[i] = 0.f;

#pragma unroll 4
  for (int i = 0; i < 16; ++i) {
    const int n = i * 16 + sub;
    const float4 za = *(const float4*)(&zl[n * 8]);
    const float4 zb4 = *(const float4*)(&zl[n * 8 + 4]);
    const float zv[8] = {za.x, za.y, za.z, za.w, zb4.x, zb4.y, zb4.z, zb4.w};
    const float g = gl[n * 16 + k];
    gs += g;
    float t[8];
#pragma unroll
    for (int l = 0; l < 8; ++l) { t[l] = g * zv[l]; m1[l] += t[l]; }
    int p = 0;
#pragma unroll
    for (int l = 0; l < 8; ++l)
#pragma unroll
      for (int m = l; m < 8; ++m) {
        m2[p] = fmaf(t[l], zv[m], m2[p]);
        ++p;
      }
  }

#pragma unroll
  for (int i = 0; i < 36; ++i) {
    m2[i] += __shfl_xor(m2[i], 16);
    m2[i] += __shfl_xor(m2[i], 32);
  }
#pragma unroll
  for (int i = 0; i < 8; ++i) {
    m1[i] += __shfl_xor(m1[i], 16);
    m1[i] += __shfl_xor(m1[i], 32);
  }
  gs += __shfl_xor(gs, 16);
  gs += __shfl_xor(gs, 32);

  const int lane = tid & 63, wv = tid >> 6;
  if (lane < 16) {
#pragma unroll
    for (int i = 0; i < 36; ++i) red[wv][lane][i] = m2[i];
#pragma unroll
    for (int i = 0; i < 8; ++i) red[wv][lane][36 + i] = m1[i];
    red[wv][lane][44] = gs;
  }
  __syncthreads();

  for (int o = tid; o < 768; o += 256) {
    const int kk = o / 48, p = o % 48;
    float v = 0.f;
    if (p < 45)
      v = red[0][kk][p] + red[1][kk][p] + red[2][kk][p] + red[3][kk][p];
    part[(size_t)blk * 768 + o] = v;
  }
}

// ---------------------------------------------------------------------------
// K2b: reduce part[1024][768] -> stats[768]. 24 blocks.
// ---------------------------------------------------------------------------
__global__ __launch_bounds__(256) void k2b_reduce(
    const float* __restrict__ part, float* __restrict__ stats)
{
  const int oi = blockIdx.x % 3, jc = blockIdx.x / 3;
  const int o = oi * 256 + threadIdx.x;
  float s = 0.f;
#pragma unroll 4
  for (int j = jc * 128; j < jc * 128 + 128; ++j)
    s += part[(size_t)j * 768 + o];
  atomicAdd(&stats[o], s);
}

// ---------------------------------------------------------------------------
// K3: finalize GMM params -> quadratic coefficients (stats stride 48)
// ---------------------------------------------------------------------------
__global__ void k3_finalize(const float* __restrict__ stats, float* __restrict__ coef)
{
  const int k = threadIdx.x;
  if (k >= 16) return;
  const float* sk = stats + k * 48;
  const float gs = sk[44];
  float mu[8];
#pragma unroll
  for (int l = 0; l < 8; ++l) mu[l] = sk[36 + l] / gs;

  float S[8][8];
  {
    int p = 0;
    for (int l = 0; l < 8; ++l)
      for (int m = l; m < 8; ++m) {
        const float v = sk[p++] / gs - mu[l] * mu[m];
        S[l][m] = v; S[m][l] = v;
      }
  }
  for (int l = 0; l < 8; ++l) S[l][l] += 1e-6f;

  float L[8][8];
  for (int i = 0; i < 8; ++i)
    for (int j = 0; j <= i; ++j) {
      float s = S[i][j];
      for (int t = 0; t < j; ++t) s -= L[i][t] * L[j][t];
      if (i == j) L[i][i] = sqrtf(s);
      else        L[i][j] = s / L[j][j];
    }
  float logdet = 0.f;
  for (int i = 0; i < 8; ++i) logdet += logf(L[i][i]);
  logdet *= 2.f;

  float U[8][8];
  for (int j = 0; j < 8; ++j) {
    U[j][j] = 1.f / L[j][j];
    for (int i = j + 1; i < 8; ++i) {
      float s = 0.f;
      for (int t = j; t < i; ++t) s += L[i][t] * U[t][j];
      U[i][j] = -s / L[i][i];
    }
  }
  float Amat[8][8];
  for (int l = 0; l < 8; ++l)
    for (int m = l; m < 8; ++m) {
      float s = 0.f;
      for (int i = m; i < 8; ++i) s += U[i][l] * U[i][m];
      Amat[l][m] = s; Amat[m][l] = s;
    }
  float c[8];
  for (int l = 0; l < 8; ++l) {
    float s = 0.f;
    for (int m = 0; m < 8; ++m) s += Amat[l][m] * mu[m];
    c[l] = s;
  }
  float muAmu = 0.f;
  for (int l = 0; l < 8; ++l) muAmu += c[l] * mu[l];

  const float LOG2PI = 1.8378770664093453f;
  const float cnst = logf(gs) - logf((float)NSAMP)
                   - 0.5f * (8.f * LOG2PI + logdet + muAmu);

  float* ck = coef + k * 48;
  {
    int p = 0;
    for (int l = 0; l < 8; ++l)
      for (int m = l; m < 8; ++m) {
        ck[p] = (l == m) ? (-0.5f * Amat[l][l]) : (-Amat[l][m]);
        ++p;
      }
  }
  for (int l = 0; l < 8; ++l) ck[36 + l] = c[l];
  ck[44] = cnst;
  ck[45] = 0.f; ck[46] = 0.f; ck[47] = 0.f;
}

// ---------------------------------------------------------------------------
// K4: per-sample energy + online LSE
// ---------------------------------------------------------------------------
__global__ __launch_bounds__(256) void k4_energy(
    const float* __restrict__ zg, const float* __restrict__ coef,
    float* __restrict__ prob)
{
  __shared__ float C[16 * 48];
  for (int i = threadIdx.x; i < 16 * 48; i += 256) C[i] = coef[i];
  __syncthreads();

  const int n = blockIdx.x * 256 + threadIdx.x;
  const float4 za = *(const float4*)(zg + (size_t)n * 8);
  const float4 zb = *(const float4*)(zg + (size_t)n * 8 + 4);
  const float z[8] = {za.x, za.y, za.z, za.w, zb.x, zb.y, zb.z, zb.w};

  float pr[36];
  {
    int p = 0;
#pragma unroll
    for (int l = 0; l < 8; ++l)
#pragma unroll
      for (int m = l; m < 8; ++m) pr[p++] = z[l] * z[m];
  }

  float mx = -1e30f, sm = 0.f;
#pragma unroll
  for (int k = 0; k < 16; ++k) {
    const float4* c4 = (const float4*)&C[k * 48];
    float acc = C[k * 48 + 44];
#pragma unroll
    for (int q = 0; q < 9; ++q) {
      const float4 t = c4[q];
      acc = fmaf(t.x, pr[q * 4 + 0], acc);
      acc = fmaf(t.y, pr[q * 4 + 1], acc);
      acc = fmaf(t.z, pr[q * 4 + 2], acc);
      acc = fmaf(t.w, pr[q * 4 + 3], acc);
    }
    {
      const float4 t = c4[9];
      acc = fmaf(t.x, z[0], acc); acc = fmaf(t.y, z[1], acc);
      acc = fmaf(t.z, z[2], acc); acc = fmaf(t.w, z[3], acc);
    }
    {
      const float4 t = c4[10];
      acc = fmaf(t.x, z[4], acc); acc = fmaf(t.y, z[5], acc);
      acc = fmaf(t.z, z[6], acc); acc = fmaf(t.w, z[7], acc);
    }
    const float nm = fmaxf(mx, acc);
    sm = sm * __expf(mx - nm) + __expf(acc - nm);
    mx = nm;
  }
  prob[n] = -(mx + __logf(sm));
}

// ---------------------------------------------------------------------------
extern "C" void kernel_launch(void* const* d_in, const int* in_sizes, int n_in,
                              void* d_out, int out_size, void* d_ws, size_t ws_size,
                              hipStream_t stream)
{
  const float* x   = (const float*)d_in[0];
  const float* W0  = (const float*)d_in[1];
  const float* b0  = (const float*)d_in[2];
  const float* W1  = (const float*)d_in[3];
  const float* b1  = (const float*)d_in[4];
  const float* W2  = (const float*)d_in[5];
  const float* b2  = (const float*)d_in[6];
  const float* W3  = (const float*)d_in[7];
  const float* b3  = (const float*)d_in[8];
  const float* E0w = (const float*)d_in[9];
  const float* eb0 = (const float*)d_in[10];
  const float* E1w = (const float*)d_in[11];
  const float* eb1 = (const float*)d_in[12];
  const float* E2w = (const float*)d_in[13];
  const float* eb2 = (const float*)d_in[14];

  float* out  = (float*)d_out;
  float* prob = out;              // [N]
  float* zg   = out + NSAMP;      // [N][8]

  // ws: wpack (444 frags * 512 B, padded to 448 KB) | gamma [N][16]
  //   | stats 768 | coef 768 | part [1024][768]
  unsigned short* wpack = (unsigned short*)d_ws;
  float* ws    = (float*)d_ws;
  float* gamma = ws + 114688;
  float* stats = gamma + (size_t)NSAMP * 16;
  float* coef  = stats + 768;
  float* part  = coef + 768;

  hipMemsetAsync(stats, 0, 768 * sizeof(float), stream);

  k0_pack<<<444, 64, 0, stream>>>(W0, W1, W2, E1w, E0w, W3, E2w, wpack);
  k1_mfma<<<NSAMP / TMS, 256, 0, stream>>>(x, wpack, b0, b1, b2, b3,
                                           eb0, eb1, eb2, zg, gamma);
  k2a_partial<<<1024, 256, 0, stream>>>(zg, gamma, part);
  k2b_reduce<<<24, 256, 0, stream>>>(part, stats);
  k3_finalize<<<1, 64, 0, stream>>>(stats, coef);
  k4_energy<<<NSAMP / 256, 256, 0, stream>>>(zg, coef, prob);
}

// Round 14
// 212.208 us; speedup vs baseline: 1.1132x; 1.1132x over previous
//
#include <hip/hip_runtime.h>
#include <math.h>

#define NSAMP 262144
#define TMS 64   // samples per block in k1

typedef __bf16  bf16x8 __attribute__((ext_vector_type(8)));
typedef __bf16  bf16x4 __attribute__((ext_vector_type(4)));
typedef float   f32x4  __attribute__((ext_vector_type(4)));

// tanh via native exp + native rcp (1-ulp). Verified round 9: -68 us.
__device__ __forceinline__ float fast_tanh(float v) {
  float e = __expf(2.0f * v);
  return 1.0f - 2.0f * __builtin_amdgcn_rcpf(e + 1.0f);
}
__device__ __forceinline__ unsigned short f2bf(float f) {
  unsigned u = __float_as_uint(f);
  unsigned r = (u + 0x7FFFu + ((u >> 16) & 1u)) >> 16;   // RNE
  return (unsigned short)r;
}

// ---------------------------------------------------------------------------
// K0: pack all weights into bf16 MFMA *A-operand* fragments of W^T:
// lane l holds W[k = ks*32+(l>>4)*8+i][n = nt*16+(l&15)], zero-padded OOB.
// sections: L1 [0,128) NKS=4 N=512 | L2 [128,384) NKS=16 N=256
//   L3 [384,416) NKS=8 N=64 | E1 [416,432) NKS=4 N=64
//   E0 [432,440) NKS=1 N=128 K=8 | L4 [440,442) NKS=2 N=8->16 K=64
//   E2 [442,444) NKS=2 N=16 K=64
// ---------------------------------------------------------------------------
__global__ void k0_pack(const float* __restrict__ W0, const float* __restrict__ W1,
                        const float* __restrict__ W2, const float* __restrict__ E1w,
                        const float* __restrict__ E0w, const float* __restrict__ W3,
                        const float* __restrict__ E2w,
                        unsigned short* __restrict__ wpack)
{
  const int f = blockIdx.x;
  const int lane = threadIdx.x;
  const float* W; int NKS, N, Kreal, Nreal, local;
  if (f < 128)      { W = W0;  NKS = 4;  N = 512; Kreal = 128; Nreal = 512; local = f; }
  else if (f < 384) { W = W1;  NKS = 16; N = 256; Kreal = 512; Nreal = 256; local = f - 128; }
  else if (f < 416) { W = W2;  NKS = 8;  N = 64;  Kreal = 256; Nreal = 64;  local = f - 384; }
  else if (f < 432) { W = E1w; NKS = 4;  N = 64;  Kreal = 128; Nreal = 64;  local = f - 416; }
  else if (f < 440) { W = E0w; NKS = 1;  N = 128; Kreal = 8;   Nreal = 128; local = f - 432; }
  else if (f < 442) { W = W3;  NKS = 2;  N = 8;   Kreal = 64;  Nreal = 8;   local = f - 440; }
  else              { W = E2w; NKS = 2;  N = 16;  Kreal = 64;  Nreal = 16;  local = f - 442; }
  const int nt = local / NKS, ks = local % NKS;
  const int n = nt * 16 + (lane & 15);
  const int kbase = ks * 32 + (lane >> 4) * 8;
  unsigned short* out = wpack + ((size_t)f * 64 + lane) * 8;
#pragma unroll
  for (int i = 0; i < 8; ++i) {
    const int k = kbase + i;
    const float v = (k < Kreal && n < Nreal) ? W[(size_t)k * N + n] : 0.f;
    out[i] = f2bf(v);
  }
}

// ---------------------------------------------------------------------------
// Swapped-operand layer, NKS=4 (a-frags cached across tiles), 4 sample groups.
// ---------------------------------------------------------------------------
template<int NTPW>
__device__ __forceinline__ void layer_nks4(
    const char* __restrict__ in, int inRowB, char* __restrict__ outb, int outRowB,
    const unsigned short* __restrict__ wp, int fragBase,
    const float* __restrict__ bias, int lane, int wv)
{
  const int l15 = lane & 15, lg = lane >> 4;
  const int sw = (l15 & 7) << 4;
  bf16x8 a[4][4];
#pragma unroll
  for (int sg = 0; sg < 4; ++sg)
#pragma unroll
    for (int q = 0; q < 4; ++q)
      a[sg][q] = *(const bf16x8*)(in + (sg * 16 + l15) * inRowB + ((q * 64 + lg * 16) ^ sw));
#pragma unroll
  for (int t = 0; t < NTPW; ++t) {
    const int nt = wv * NTPW + t;
    const float4 bv = *(const float4*)(bias + nt * 16 + lg * 4);
    f32x4 acc[4];
#pragma unroll
    for (int sg = 0; sg < 4; ++sg) acc[sg] = {bv.x, bv.y, bv.z, bv.w};
#pragma unroll
    for (int q = 0; q < 4; ++q) {
      const bf16x8 w = *(const bf16x8*)(wp + ((size_t)(fragBase + nt * 4 + q) * 64 + lane) * 8);
#pragma unroll
      for (int sg = 0; sg < 4; ++sg)
        acc[sg] = __builtin_amdgcn_mfma_f32_16x16x32_bf16(w, a[sg][q], acc[sg], 0, 0, 0);
    }
#pragma unroll
    for (int sg = 0; sg < 4; ++sg) {
      bf16x4 tv;
#pragma unroll
      for (int r = 0; r < 4; ++r) tv[r] = (__bf16)fast_tanh(acc[sg][r]);
      *(bf16x4*)(outb + (sg * 16 + l15) * outRowB + ((nt * 32 + lg * 8) ^ sw)) = tv;
    }
  }
}

// ---------------------------------------------------------------------------
// L2 partial accumulation: K-half of 256 (2 chunks x 4 kfrags) into persistent
// acc[4 tiles][4 sg]. H1 rows 512B hold the current L1 half (relative k).
// ---------------------------------------------------------------------------
template<int NCH>
__device__ __forceinline__ void l2_accum(
    const char* __restrict__ H1, const unsigned short* __restrict__ wp,
    int ksOff, f32x4 (&acc)[4][4], int lane, int wv)
{
  const int l15 = lane & 15, lg = lane >> 4;
  const int sw = (l15 & 7) << 4;
#pragma unroll
  for (int ch = 0; ch < NCH; ++ch) {
    bf16x8 a[4][4];
#pragma unroll
    for (int sg = 0; sg < 4; ++sg)
#pragma unroll
      for (int q = 0; q < 4; ++q)
        a[sg][q] = *(const bf16x8*)(H1 + (sg * 16 + l15) * 512 + (((ch * 4 + q) * 64 + lg * 16) ^ sw));
#pragma unroll
    for (int t = 0; t < 4; ++t) {
      const int nt = wv * 4 + t;
#pragma unroll
      for (int q = 0; q < 4; ++q) {
        const bf16x8 w = *(const bf16x8*)(wp + ((size_t)(128 + nt * 16 + ksOff + ch * 4 + q) * 64 + lane) * 8);
#pragma unroll
        for (int sg = 0; sg < 4; ++sg)
          acc[t][sg] = __builtin_amdgcn_mfma_f32_16x16x32_bf16(w, a[sg][q], acc[t][sg], 0, 0, 0);
      }
    }
  }
}

// ---------------------------------------------------------------------------
// K1: fused MLP, R9 core (TMS=64, 80KB LDS, half-pass L1/L2, 2 blocks/CU)
// + WAVE-LOCAL TAIL: after L3's input barrier, wave wv owns samples
// [wv*16, wv*16+16) through L3/L4/E0/E1/E2 -> ZERO tail barriers (same-wave
// LDS produce->consume is in-order; cross-wave LDS rows disjoint).
//  H1 [0,32K): L1out half -> E0o (rows 256B, wave-local rows)
//  H2 [32K,64K): L2out (last read: L3)
//  X  [64K,80K): x tile -> L3o (8K, rows 128B) -> e1 aliases L3o rows; zb @+73728
// ---------------------------------------------------------------------------
__global__ __launch_bounds__(256, 2) void k1_mfma(
    const float* __restrict__ x, const unsigned short* __restrict__ wpack,
    const float* __restrict__ b0, const float* __restrict__ b1,
    const float* __restrict__ b2, const float* __restrict__ b3,
    const float* __restrict__ eb0, const float* __restrict__ eb1,
    const float* __restrict__ eb2,
    float* __restrict__ zg, float* __restrict__ gamma)
{
  __shared__ char sm[81920];
  char* H1  = sm;                    // 32 KB, rows 512B
  char* H2  = sm + 32768;            // 32 KB, rows 512B
  char* X   = sm + 65536;            // 16 KB, rows 256B
  char* L3o = sm + 65536;            // 8 KB, rows 128B (after X dead)
  char* zb  = sm + 73728;            // [64][16B] bf16 z, 1 KB
  char* E0o = sm;                    // rows 256B (after H1 dead)
  char* e1  = sm + 65536;            // = L3o rows (safe: same-wave WAR, rows disjoint across waves)

  const int tid = threadIdx.x;
  const int lane = tid & 63, wv = tid >> 6;
  const int l15 = lane & 15, lg = lane >> 4;
  const int sw = (l15 & 7) << 4;
  const int blk = blockIdx.x;

  // ---- stage x -> X: bf16 [64][128], swizzled ----
  {
    const float* xb = x + (size_t)blk * (TMS * 128);
#pragma unroll
    for (int p = 0; p < 8; ++p) {
      const int v = tid + p * 256;
      const float4 t = *(const float4*)(xb + v * 4);
      const int s = v >> 5, k0 = (v & 31) * 4;
      bf16x4 h = {(__bf16)t.x, (__bf16)t.y, (__bf16)t.z, (__bf16)t.w};
      *(bf16x4*)(X + s * 256 + ((k0 * 2) ^ ((s & 7) << 4))) = h;
    }
  }

  // L2 persistent accumulators, bias-initialized
  f32x4 acc2[4][4];
#pragma unroll
  for (int t = 0; t < 4; ++t) {
    const float4 bv = *(const float4*)(b1 + (wv * 4 + t) * 16 + lg * 4);
#pragma unroll
    for (int sg = 0; sg < 4; ++sg) acc2[t][sg] = {bv.x, bv.y, bv.z, bv.w};
  }
  __syncthreads();

  layer_nks4<4>(X, 256, H1, 512, wpack, 0, b0, lane, wv);         // L1 n 0..255
  __syncthreads();
  l2_accum<2>(H1, wpack, 0, acc2, lane, wv);                      // L2 k 0..255
  __syncthreads();
  layer_nks4<4>(X, 256, H1, 512, wpack, 64, b0 + 256, lane, wv);  // L1 n 256..511
  __syncthreads();
  l2_accum<2>(H1, wpack, 8, acc2, lane, wv);                      // L2 k 256..511

  // L2 epilogue -> H2
#pragma unroll
  for (int t = 0; t < 4; ++t)
#pragma unroll
    for (int sg = 0; sg < 4; ++sg) {
      bf16x4 tv;
#pragma unroll
      for (int r = 0; r < 4; ++r) tv[r] = (__bf16)fast_tanh(acc2[t][sg][r]);
      *(bf16x4*)(H2 + (sg * 16 + l15) * 512 + (((wv * 4 + t) * 32 + lg * 8) ^ sw)) = tv;
    }
  __syncthreads();
  // ======== wave-local tail: no further __syncthreads ========

  // ---- L3: 256 -> 64 tanh; wave-local: all 4 n-tiles for sg = wv ----
  {
    f32x4 acc3[4];
#pragma unroll
    for (int nt = 0; nt < 4; ++nt) {
      const float4 bv = *(const float4*)(b2 + nt * 16 + lg * 4);
      acc3[nt] = {bv.x, bv.y, bv.z, bv.w};
    }
#pragma unroll
    for (int ch = 0; ch < 2; ++ch) {
      bf16x8 a[4];
#pragma unroll
      for (int q = 0; q < 4; ++q)
        a[q] = *(const bf16x8*)(H2 + (wv * 16 + l15) * 512 + (((ch * 4 + q) * 64 + lg * 16) ^ sw));
#pragma unroll
      for (int nt = 0; nt < 4; ++nt)
#pragma unroll
        for (int q = 0; q < 4; ++q) {
          const bf16x8 w = *(const bf16x8*)(wpack + ((size_t)(384 + nt * 8 + ch * 4 + q) * 64 + lane) * 8);
          acc3[nt] = __builtin_amdgcn_mfma_f32_16x16x32_bf16(w, a[q], acc3[nt], 0, 0, 0);
        }
    }
#pragma unroll
    for (int nt = 0; nt < 4; ++nt) {
      bf16x4 tv;
#pragma unroll
      for (int r = 0; r < 4; ++r) tv[r] = (__bf16)fast_tanh(acc3[nt][r]);
      *(bf16x4*)(L3o + (wv * 16 + l15) * 128 + ((nt * 32 + lg * 8) ^ sw)) = tv;
    }
  }

  // ---- L4: 64 -> 8 (N padded 16); wave-local sg = wv ----
  {
    bf16x8 a[2];
#pragma unroll
    for (int q = 0; q < 2; ++q)
      a[q] = *(const bf16x8*)(L3o + (wv * 16 + l15) * 128 + ((q * 64 + lg * 16) ^ sw));
    float4 bv = {0.f, 0.f, 0.f, 0.f};
    if (lg < 2) bv = *(const float4*)(b3 + lg * 4);
    f32x4 acc = {bv.x, bv.y, bv.z, bv.w};
#pragma unroll
    for (int q = 0; q < 2; ++q) {
      const bf16x8 w = *(const bf16x8*)(wpack + ((size_t)(440 + q) * 64 + lane) * 8);
      acc = __builtin_amdgcn_mfma_f32_16x16x32_bf16(w, a[q], acc, 0, 0, 0);
    }
    if (lg < 2) {
      *(f32x4*)(zg + ((size_t)blk * 64 + wv * 16 + l15) * 8 + lg * 4) = acc;
      bf16x4 zv;
#pragma unroll
      for (int r = 0; r < 4; ++r) zv[r] = (__bf16)acc[r];
      *(bf16x4*)(zb + (wv * 16 + l15) * 16 + lg * 8) = zv;
    }
  }

  // ---- E0: 8 -> 128 tanh (K padded 32, zero weights kill k>=8); wave-local ----
  {
    const bf16x8 az = *(const bf16x8*)(zb + (wv * 16 + l15) * 16);
#pragma unroll
    for (int nt = 0; nt < 8; ++nt) {
      const float4 bv = *(const float4*)(eb0 + nt * 16 + lg * 4);
      const bf16x8 w = *(const bf16x8*)(wpack + ((size_t)(432 + nt) * 64 + lane) * 8);
      f32x4 acc = {bv.x, bv.y, bv.z, bv.w};
      acc = __builtin_amdgcn_mfma_f32_16x16x32_bf16(w, az, acc, 0, 0, 0);
      bf16x4 tv;
#pragma unroll
      for (int r = 0; r < 4; ++r) tv[r] = (__bf16)fast_tanh(acc[r]);
      *(bf16x4*)(E0o + (wv * 16 + l15) * 256 + ((nt * 32 + lg * 8) ^ sw)) = tv;
    }
  }

  // ---- E1: 128 -> 64 tanh; wave-local (out -> e1 = own L3o rows, WAR safe) ----
  {
    bf16x8 a[4];
#pragma unroll
    for (int q = 0; q < 4; ++q)
      a[q] = *(const bf16x8*)(E0o + (wv * 16 + l15) * 256 + ((q * 64 + lg * 16) ^ sw));
#pragma unroll
    for (int nt = 0; nt < 4; ++nt) {
      const float4 bv = *(const float4*)(eb1 + nt * 16 + lg * 4);
      f32x4 acc = {bv.x, bv.y, bv.z, bv.w};
#pragma unroll
      for (int q = 0; q < 4; ++q) {
        const bf16x8 w = *(const bf16x8*)(wpack + ((size_t)(416 + nt * 4 + q) * 64 + lane) * 8);
        acc = __builtin_amdgcn_mfma_f32_16x16x32_bf16(w, a[q], acc, 0, 0, 0);
      }
      bf16x4 tv;
#pragma unroll
      for (int r = 0; r < 4; ++r) tv[r] = (__bf16)fast_tanh(acc[r]);
      *(bf16x4*)(e1 + (wv * 16 + l15) * 128 + ((nt * 32 + lg * 8) ^ sw)) = tv;
    }
  }

  // ---- E2 + softmax; wave-local ----
  {
    bf16x8 a[2];
#pragma unroll
    for (int q = 0; q < 2; ++q)
      a[q] = *(const bf16x8*)(e1 + (wv * 16 + l15) * 128 + ((q * 64 + lg * 16) ^ sw));
    const float4 bv = *(const float4*)(eb2 + lg * 4);
    f32x4 acc = {bv.x, bv.y, bv.z, bv.w};
#pragma unroll
    for (int q = 0; q < 2; ++q) {
      const bf16x8 w = *(const bf16x8*)(wpack + ((size_t)(442 + q) * 64 + lane) * 8);
      acc = __builtin_amdgcn_mfma_f32_16x16x32_bf16(w, a[q], acc, 0, 0, 0);
    }
    float m = fmaxf(fmaxf(acc[0], acc[1]), fmaxf(acc[2], acc[3]));
    m = fmaxf(m, __shfl_xor(m, 16));
    m = fmaxf(m, __shfl_xor(m, 32));
    float e0v = __expf(acc[0] - m), e1v = __expf(acc[1] - m);
    float e2v = __expf(acc[2] - m), e3v = __expf(acc[3] - m);
    float s = e0v + e1v + e2v + e3v;
    s += __shfl_xor(s, 16);
    s += __shfl_xor(s, 32);
    const float inv = __builtin_amdgcn_rcpf(s);
    float4 g = {e0v * inv, e1v * inv, e2v * inv, e3v * inv};
    *(float4*)(gamma + ((size_t)blk * 64 + wv * 16 + l15) * 16 + lg * 4) = g;
  }
}

// ---------------------------------------------------------------------------
// K2a: moment partials. 1024 blocks x 256 samples each, LDS-staged.
// ---------------------------------------------------------------------------
__global__ __launch_bounds__(256) void k2a_partial(
    const float* __restrict__ zg, const float* __restrict__ gamma,
    float* __restrict__ part)
{
  __shared__ float zl[256 * 8];
  __shared__ float gl[256 * 16];
  __shared__ float red[4][16][46];
  const int tid = threadIdx.x;
  const int blk = blockIdx.x;
  const int s0 = blk * 256;

  {
    const float4 a = *(const float4*)(zg + (size_t)(s0 + tid) * 8);
    const float4 b = *(const float4*)(zg + (size_t)(s0 + tid) * 8 + 4);
    *(float4*)(&zl[tid * 8])     = a;
    *(float4*)(&zl[tid * 8 + 4]) = b;
  }
  {
    const float* gp = gamma + (size_t)(s0 + tid) * 16;
#pragma unroll
    for (int q = 0; q < 4; ++q)
      *(float4*)(&gl[tid * 16 + q * 4]) = *(const float4*)(gp + q * 4);
  }
  __syncthreads();

  const int k = tid & 15, sub = tid >> 4;
  float m2[36], m1[8], gs = 0.f;
#pragma unroll
  for (int i = 0; i < 36; ++i) m2[i] = 0.f;
#pragma unroll
  for (int i = 0; i < 8; ++i) m1[i] = 0.f;

#pragma unroll 4
  for (int i = 0; i < 16; ++i) {
    const int n = i * 16 + sub;
    const float4 za = *(const float4*)(&zl[n * 8]);
    const float4 zb4 = *(const float4*)(&zl[n * 8 + 4]);
    const float zv[8] = {za.x, za.y, za.z, za.w, zb4.x, zb4.y, zb4.z, zb4.w};
    const float g = gl[n * 16 + k];
    gs += g;
    float t[8];
#pragma unroll
    for (int l = 0; l < 8; ++l) { t[l] = g * zv[l]; m1[l] += t[l]; }
    int p = 0;
#pragma unroll
    for (int l = 0; l < 8; ++l)
#pragma unroll
      for (int m = l; m < 8; ++m) {
        m2[p] = fmaf(t[l], zv[m], m2[p]);
        ++p;
      }
  }

#pragma unroll
  for (int i = 0; i < 36; ++i) {
    m2[i] += __shfl_xor(m2[i], 16);
    m2[i] += __shfl_xor(m2[i], 32);
  }
#pragma unroll
  for (int i = 0; i < 8; ++i) {
    m1[i] += __shfl_xor(m1[i], 16);
    m1[i] += __shfl_xor(m1[i], 32);
  }
  gs += __shfl_xor(gs, 16);
  gs += __shfl_xor(gs, 32);

  const int lane = tid & 63, wv = tid >> 6;
  if (lane < 16) {
#pragma unroll
    for (int i = 0; i < 36; ++i) red[wv][lane][i] = m2[i];
#pragma unroll
    for (int i = 0; i < 8; ++i) red[wv][lane][36 + i] = m1[i];
    red[wv][lane][44] = gs;
  }
  __syncthreads();

  for (int o = tid; o < 768; o += 256) {
    const int kk = o / 48, p = o % 48;
    float v = 0.f;
    if (p < 45)
      v = red[0][kk][p] + red[1][kk][p] + red[2][kk][p] + red[3][kk][p];
    part[(size_t)blk * 768 + o] = v;
  }
}

// ---------------------------------------------------------------------------
// K2b: reduce part[1024][768] -> stats[768]. 24 blocks.
// ---------------------------------------------------------------------------
__global__ __launch_bounds__(256) void k2b_reduce(
    const float* __restrict__ part, float* __restrict__ stats)
{
  const int oi = blockIdx.x % 3, jc = blockIdx.x / 3;
  const int o = oi * 256 + threadIdx.x;
  float s = 0.f;
#pragma unroll 4
  for (int j = jc * 128; j < jc * 128 + 128; ++j)
    s += part[(size_t)j * 768 + o];
  atomicAdd(&stats[o], s);
}

// ---------------------------------------------------------------------------
// K3: finalize GMM params -> quadratic coefficients (stats stride 48)
// ---------------------------------------------------------------------------
__global__ void k3_finalize(const float* __restrict__ stats, float* __restrict__ coef)
{
  const int k = threadIdx.x;
  if (k >= 16) return;
  const float* sk = stats + k * 48;
  const float gs = sk[44];
  float mu[8];
#pragma unroll
  for (int l = 0; l < 8; ++l) mu[l] = sk[36 + l] / gs;

  float S[8][8];
  {
    int p = 0;
    for (int l = 0; l < 8; ++l)
      for (int m = l; m < 8; ++m) {
        const float v = sk[p++] / gs - mu[l] * mu[m];
        S[l][m] = v; S[m][l] = v;
      }
  }
  for (int l = 0; l < 8; ++l) S[l][l] += 1e-6f;

  float L[8][8];
  for (int i = 0; i < 8; ++i)
    for (int j = 0; j <= i; ++j) {
      float s = S[i][j];
      for (int t = 0; t < j; ++t) s -= L[i][t] * L[j][t];
      if (i == j) L[i][i] = sqrtf(s);
      else        L[i][j] = s / L[j][j];
    }
  float logdet = 0.f;
  for (int i = 0; i < 8; ++i) logdet += logf(L[i][i]);
  logdet *= 2.f;

  float U[8][8];
  for (int j = 0; j < 8; ++j) {
    U[j][j] = 1.f / L[j][j];
    for (int i = j + 1; i < 8; ++i) {
      float s = 0.f;
      for (int t = j; t < i; ++t) s += L[i][t] * U[t][j];
      U[i][j] = -s / L[i][i];
    }
  }
  float Amat[8][8];
  for (int l = 0; l < 8; ++l)
    for (int m = l; m < 8; ++m) {
      float s = 0.f;
      for (int i = m; i < 8; ++i) s += U[i][l] * U[i][m];
      Amat[l][m] = s; Amat[m][l] = s;
    }
  float c[8];
  for (int l = 0; l < 8; ++l) {
    float s = 0.f;
    for (int m = 0; m < 8; ++m) s += Amat[l][m] * mu[m];
    c[l] = s;
  }
  float muAmu = 0.f;
  for (int l = 0; l < 8; ++l) muAmu += c[l] * mu[l];

  const float LOG2PI = 1.8378770664093453f;
  const float cnst = logf(gs) - logf((float)NSAMP)
                   - 0.5f * (8.f * LOG2PI + logdet + muAmu);

  float* ck = coef + k * 48;
  {
    int p = 0;
    for (int l = 0; l < 8; ++l)
      for (int m = l; m < 8; ++m) {
        ck[p] = (l == m) ? (-0.5f * Amat[l][l]) : (-Amat[l][m]);
        ++p;
      }
  }
  for (int l = 0; l < 8; ++l) ck[36 + l] = c[l];
  ck[44] = cnst;
  ck[45] = 0.f; ck[46] = 0.f; ck[47] = 0.f;
}

// ---------------------------------------------------------------------------
// K4: per-sample energy + online LSE
// ---------------------------------------------------------------------------
__global__ __launch_bounds__(256) void k4_energy(
    const float* __restrict__ zg, const float* __restrict__ coef,
    float* __restrict__ prob)
{
  __shared__ float C[16 * 48];
  for (int i = threadIdx.x; i < 16 * 48; i += 256) C[i] = coef[i];
  __syncthreads();

  const int n = blockIdx.x * 256 + threadIdx.x;
  const float4 za = *(const float4*)(zg + (size_t)n * 8);
  const float4 zb = *(const float4*)(zg + (size_t)n * 8 + 4);
  const float z[8] = {za.x, za.y, za.z, za.w, zb.x, zb.y, zb.z, zb.w};

  float pr[36];
  {
    int p = 0;
#pragma unroll
    for (int l = 0; l < 8; ++l)
#pragma unroll
      for (int m = l; m < 8; ++m) pr[p++] = z[l] * z[m];
  }

  float mx = -1e30f, sm = 0.f;
#pragma unroll
  for (int k = 0; k < 16; ++k) {
    const float4* c4 = (const float4*)&C[k * 48];
    float acc = C[k * 48 + 44];
#pragma unroll
    for (int q = 0; q < 9; ++q) {
      const float4 t = c4[q];
      acc = fmaf(t.x, pr[q * 4 + 0], acc);
      acc = fmaf(t.y, pr[q * 4 + 1], acc);
      acc = fmaf(t.z, pr[q * 4 + 2], acc);
      acc = fmaf(t.w, pr[q * 4 + 3], acc);
    }
    {
      const float4 t = c4[9];
      acc = fmaf(t.x, z[0], acc); acc = fmaf(t.y, z[1], acc);
      acc = fmaf(t.z, z[2], acc); acc = fmaf(t.w, z[3], acc);
    }
    {
      const float4 t = c4[10];
      acc = fmaf(t.x, z[4], acc); acc = fmaf(t.y, z[5], acc);
      acc = fmaf(t.z, z[6], acc); acc = fmaf(t.w, z[7], acc);
    }
    const float nm = fmaxf(mx, acc);
    sm = sm * __expf(mx - nm) + __expf(acc - nm);
    mx = nm;
  }
  prob[n] = -(mx + __logf(sm));
}

// ---------------------------------------------------------------------------
extern "C" void kernel_launch(void* const* d_in, const int* in_sizes, int n_in,
                              void* d_out, int out_size, void* d_ws, size_t ws_size,
                              hipStream_t stream)
{
  const float* x   = (const float*)d_in[0];
  const float* W0  = (const float*)d_in[1];
  const float* b0  = (const float*)d_in[2];
  const float* W1  = (const float*)d_in[3];
  const float* b1  = (const float*)d_in[4];
  const float* W2  = (const float*)d_in[5];
  const float* b2  = (const float*)d_in[6];
  const float* W3  = (const float*)d_in[7];
  const float* b3  = (const float*)d_in[8];
  const float* E0w = (const float*)d_in[9];
  const float* eb0 = (const float*)d_in[10];
  const float* E1w = (const float*)d_in[11];
  const float* eb1 = (const float*)d_in[12];
  const float* E2w = (const float*)d_in[13];
  const float* eb2 = (const float*)d_in[14];

  float* out  = (float*)d_out;
  float* prob = out;              // [N]
  float* zg   = out + NSAMP;      // [N][8]

  // ws: wpack (444 frags * 512 B, padded to 448 KB) | gamma [N][16]
  //   | stats 768 | coef 768 | part [1024][768]
  unsigned short* wpack = (unsigned short*)d_ws;
  float* ws    = (float*)d_ws;
  float* gamma = ws + 114688;
  float* stats = gamma + (size_t)NSAMP * 16;
  float* coef  = stats + 768;
  float* part  = coef + 768;

  hipMemsetAsync(stats, 0, 768 * sizeof(float), stream);

  k0_pack<<<444, 64, 0, stream>>>(W0, W1, W2, E1w, E0w, W3, E2w, wpack);
  k1_mfma<<<NSAMP / TMS, 256, 0, stream>>>(x, wpack, b0, b1, b2, b3,
                                           eb0, eb1, eb2, zg, gamma);
  k2a_partial<<<1024, 256, 0, stream>>>(zg, gamma, part);
  k2b_reduce<<<24, 256, 0, stream>>>(part, stats);
  k3_finalize<<<1, 64, 0, stream>>>(stats, coef);
  k4_energy<<<NSAMP / 256, 256, 0, stream>>>(zg, coef, prob);
}

// Round 15
// 204.259 us; speedup vs baseline: 1.1565x; 1.0389x over previous
//
#include <hip/hip_runtime.h>
#include <math.h>

#define NSAMP 262144
#define TMS 64   // samples per block in k1

typedef __bf16  bf16x8 __attribute__((ext_vector_type(8)));
typedef __bf16  bf16x4 __attribute__((ext_vector_type(4)));
typedef float   f32x4  __attribute__((ext_vector_type(4)));

// tanh via native exp + native rcp (1-ulp): avoids the ~10-inst correctly-
// rounded f32 division sequence (no fast-math). Verified round 9: -68 us.
__device__ __forceinline__ float fast_tanh(float v) {
  float e = __expf(2.0f * v);
  return 1.0f - 2.0f * __builtin_amdgcn_rcpf(e + 1.0f);
}
__device__ __forceinline__ unsigned short f2bf(float f) {
  unsigned u = __float_as_uint(f);
  unsigned r = (u + 0x7FFFu + ((u >> 16) & 1u)) >> 16;   // RNE
  return (unsigned short)r;
}

// ---------------------------------------------------------------------------
// K0: pack all weights into bf16 MFMA *A-operand* fragments of W^T:
// lane l holds W[k = ks*32+(l>>4)*8+i][n = nt*16+(l&15)], zero-padded OOB.
// sections: L1 [0,128) NKS=4 N=512 | L2 [128,384) NKS=16 N=256
//   L3 [384,416) NKS=8 N=64 | E1 [416,432) NKS=4 N=64
//   E0 [432,440) NKS=1 N=128 K=8 | L4 [440,442) NKS=2 N=8->16 K=64
//   E2 [442,444) NKS=2 N=16 K=64
// ---------------------------------------------------------------------------
__global__ void k0_pack(const float* __restrict__ W0, const float* __restrict__ W1,
                        const float* __restrict__ W2, const float* __restrict__ E1w,
                        const float* __restrict__ E0w, const float* __restrict__ W3,
                        const float* __restrict__ E2w,
                        unsigned short* __restrict__ wpack)
{
  const int f = blockIdx.x;
  const int lane = threadIdx.x;
  const float* W; int NKS, N, Kreal, Nreal, local;
  if (f < 128)      { W = W0;  NKS = 4;  N = 512; Kreal = 128; Nreal = 512; local = f; }
  else if (f < 384) { W = W1;  NKS = 16; N = 256; Kreal = 512; Nreal = 256; local = f - 128; }
  else if (f < 416) { W = W2;  NKS = 8;  N = 64;  Kreal = 256; Nreal = 64;  local = f - 384; }
  else if (f < 432) { W = E1w; NKS = 4;  N = 64;  Kreal = 128; Nreal = 64;  local = f - 416; }
  else if (f < 440) { W = E0w; NKS = 1;  N = 128; Kreal = 8;   Nreal = 128; local = f - 432; }
  else if (f < 442) { W = W3;  NKS = 2;  N = 8;   Kreal = 64;  Nreal = 8;   local = f - 440; }
  else              { W = E2w; NKS = 2;  N = 16;  Kreal = 64;  Nreal = 16;  local = f - 442; }
  const int nt = local / NKS, ks = local % NKS;
  const int n = nt * 16 + (lane & 15);
  const int kbase = ks * 32 + (lane >> 4) * 8;
  unsigned short* out = wpack + ((size_t)f * 64 + lane) * 8;
#pragma unroll
  for (int i = 0; i < 8; ++i) {
    const int k = kbase + i;
    const float v = (k < Kreal && n < Nreal) ? W[(size_t)k * N + n] : 0.f;
    out[i] = f2bf(v);
  }
}

// ---------------------------------------------------------------------------
// Swapped-operand layer, NKS=4 (a-frags cached across tiles), 4 sample groups.
// ---------------------------------------------------------------------------
template<int NTPW>
__device__ __forceinline__ void layer_nks4(
    const char* __restrict__ in, int inRowB, char* __restrict__ outb, int outRowB,
    const unsigned short* __restrict__ wp, int fragBase,
    const float* __restrict__ bias, int lane, int wv)
{
  const int l15 = lane & 15, lg = lane >> 4;
  const int sw = (l15 & 7) << 4;
  bf16x8 a[4][4];
#pragma unroll
  for (int sg = 0; sg < 4; ++sg)
#pragma unroll
    for (int q = 0; q < 4; ++q)
      a[sg][q] = *(const bf16x8*)(in + (sg * 16 + l15) * inRowB + ((q * 64 + lg * 16) ^ sw));
#pragma unroll
  for (int t = 0; t < NTPW; ++t) {
    const int nt = wv * NTPW + t;
    const float4 bv = *(const float4*)(bias + nt * 16 + lg * 4);
    f32x4 acc[4];
#pragma unroll
    for (int sg = 0; sg < 4; ++sg) acc[sg] = {bv.x, bv.y, bv.z, bv.w};
#pragma unroll
    for (int q = 0; q < 4; ++q) {
      const bf16x8 w = *(const bf16x8*)(wp + ((size_t)(fragBase + nt * 4 + q) * 64 + lane) * 8);
#pragma unroll
      for (int sg = 0; sg < 4; ++sg)
        acc[sg] = __builtin_amdgcn_mfma_f32_16x16x32_bf16(w, a[sg][q], acc[sg], 0, 0, 0);
    }
#pragma unroll
    for (int sg = 0; sg < 4; ++sg) {
      bf16x4 tv;
#pragma unroll
      for (int r = 0; r < 4; ++r) tv[r] = (__bf16)fast_tanh(acc[sg][r]);
      *(bf16x4*)(outb + (sg * 16 + l15) * outRowB + ((nt * 32 + lg * 8) ^ sw)) = tv;
    }
  }
}

// ---------------------------------------------------------------------------
// L2 partial accumulation: K-half of 256 (2 chunks x 4 kfrags) into persistent
// acc[4 tiles][4 sg]. H1 rows 512B hold the current L1 half (relative k).
// ---------------------------------------------------------------------------
template<int NCH>
__device__ __forceinline__ void l2_accum(
    const char* __restrict__ H1, const unsigned short* __restrict__ wp,
    int ksOff, f32x4 (&acc)[4][4], int lane, int wv)
{
  const int l15 = lane & 15, lg = lane >> 4;
  const int sw = (l15 & 7) << 4;
#pragma unroll
  for (int ch = 0; ch < NCH; ++ch) {
    bf16x8 a[4][4];
#pragma unroll
    for (int sg = 0; sg < 4; ++sg)
#pragma unroll
      for (int q = 0; q < 4; ++q)
        a[sg][q] = *(const bf16x8*)(H1 + (sg * 16 + l15) * 512 + (((ch * 4 + q) * 64 + lg * 16) ^ sw));
#pragma unroll
    for (int t = 0; t < 4; ++t) {
      const int nt = wv * 4 + t;
#pragma unroll
      for (int q = 0; q < 4; ++q) {
        const bf16x8 w = *(const bf16x8*)(wp + ((size_t)(128 + nt * 16 + ksOff + ch * 4 + q) * 64 + lane) * 8);
#pragma unroll
        for (int sg = 0; sg < 4; ++sg)
          acc[t][sg] = __builtin_amdgcn_mfma_f32_16x16x32_bf16(w, a[sg][q], acc[t][sg], 0, 0, 0);
      }
    }
  }
}

// ---------------------------------------------------------------------------
// K1: fused MLP, TMS=64, half-pass L1/L2. LDS 80 KB -> 2 blocks/CU.
//  H1 [0,32K): L1out half -> (reuse) E0out
//  H2 [32K,64K): L2out -> (reuse) e1
//  X  [64K,80K): x tile -> (reuse) L3out + z-bf16
// ---------------------------------------------------------------------------
__global__ __launch_bounds__(256, 2) void k1_mfma(
    const float* __restrict__ x, const unsigned short* __restrict__ wpack,
    const float* __restrict__ b0, const float* __restrict__ b1,
    const float* __restrict__ b2, const float* __restrict__ b3,
    const float* __restrict__ eb0, const float* __restrict__ eb1,
    const float* __restrict__ eb2,
    float* __restrict__ zg, float* __restrict__ gamma)
{
  __shared__ char sm[81920];
  char* H1  = sm;                   // 32 KB, rows 512B
  char* H2  = sm + 32768;           // 32 KB, rows 512B
  char* X   = sm + 65536;           // 16 KB, rows 256B
  char* L3o = sm + 65536;           // 8 KB, rows 128B (after X dead)
  char* zb  = sm + 73728;           // 1 KB: z bf16 [64][8], rows 16B
  char* E0o = sm;                   // 16 KB, rows 256B (after H1 dead)
  char* e1  = sm + 32768;           // 8 KB, rows 128B (after H2 dead)

  const int tid = threadIdx.x;
  const int lane = tid & 63, wv = tid >> 6;
  const int l15 = lane & 15, lg = lane >> 4;
  const int sw = (l15 & 7) << 4;
  const int blk = blockIdx.x;

  // ---- stage x -> X: bf16 [64][128], swizzled ----
  {
    const float* xb = x + (size_t)blk * (TMS * 128);
#pragma unroll
    for (int p = 0; p < 8; ++p) {
      const int v = tid + p * 256;
      const float4 t = *(const float4*)(xb + v * 4);
      const int s = v >> 5, k0 = (v & 31) * 4;
      bf16x4 h = {(__bf16)t.x, (__bf16)t.y, (__bf16)t.z, (__bf16)t.w};
      *(bf16x4*)(X + s * 256 + ((k0 * 2) ^ ((s & 7) << 4))) = h;
    }
  }

  // L2 persistent accumulators, bias-initialized
  f32x4 acc2[4][4];
#pragma unroll
  for (int t = 0; t < 4; ++t) {
    const float4 bv = *(const float4*)(b1 + (wv * 4 + t) * 16 + lg * 4);
#pragma unroll
    for (int sg = 0; sg < 4; ++sg) acc2[t][sg] = {bv.x, bv.y, bv.z, bv.w};
  }
  __syncthreads();

  layer_nks4<4>(X, 256, H1, 512, wpack, 0, b0, lane, wv);         // L1 n 0..255
  __syncthreads();
  l2_accum<2>(H1, wpack, 0, acc2, lane, wv);                      // L2 k 0..255
  __syncthreads();
  layer_nks4<4>(X, 256, H1, 512, wpack, 64, b0 + 256, lane, wv);  // L1 n 256..511
  __syncthreads();
  l2_accum<2>(H1, wpack, 8, acc2, lane, wv);                      // L2 k 256..511

  // L2 epilogue -> H2
#pragma unroll
  for (int t = 0; t < 4; ++t)
#pragma unroll
    for (int sg = 0; sg < 4; ++sg) {
      bf16x4 tv;
#pragma unroll
      for (int r = 0; r < 4; ++r) tv[r] = (__bf16)fast_tanh(acc2[t][sg][r]);
      *(bf16x4*)(H2 + (sg * 16 + l15) * 512 + (((wv * 4 + t) * 32 + lg * 8) ^ sw)) = tv;
    }
  __syncthreads();

  // ---- L3: 256 -> 64 tanh; nt = wv ----
  {
    f32x4 acc[4];
    const float4 bv = *(const float4*)(b2 + wv * 16 + lg * 4);
#pragma unroll
    for (int sg = 0; sg < 4; ++sg) acc[sg] = {bv.x, bv.y, bv.z, bv.w};
#pragma unroll
    for (int ch = 0; ch < 2; ++ch) {
      bf16x8 a[4][4];
#pragma unroll
      for (int sg = 0; sg < 4; ++sg)
#pragma unroll
        for (int q = 0; q < 4; ++q)
          a[sg][q] = *(const bf16x8*)(H2 + (sg * 16 + l15) * 512 + (((ch * 4 + q) * 64 + lg * 16) ^ sw));
#pragma unroll
      for (int q = 0; q < 4; ++q) {
        const bf16x8 w = *(const bf16x8*)(wpack + ((size_t)(384 + wv * 8 + ch * 4 + q) * 64 + lane) * 8);
#pragma unroll
        for (int sg = 0; sg < 4; ++sg)
          acc[sg] = __builtin_amdgcn_mfma_f32_16x16x32_bf16(w, a[sg][q], acc[sg], 0, 0, 0);
      }
    }
#pragma unroll
    for (int sg = 0; sg < 4; ++sg) {
      bf16x4 tv;
#pragma unroll
      for (int r = 0; r < 4; ++r) tv[r] = (__bf16)fast_tanh(acc[sg][r]);
      *(bf16x4*)(L3o + (sg * 16 + l15) * 128 + ((wv * 32 + lg * 8) ^ sw)) = tv;
    }
  }
  __syncthreads();

  // ---- L4: 64 -> 8 (N padded 16); sample group = wv.
  // z written fp32 to global (output) and bf16 to LDS (E0 operand). ----
  {
    bf16x8 a[2];
#pragma unroll
    for (int q = 0; q < 2; ++q)
      a[q] = *(const bf16x8*)(L3o + (wv * 16 + l15) * 128 + ((q * 64 + lg * 16) ^ sw));
    float4 bv = {0.f, 0.f, 0.f, 0.f};
    if (lg < 2) bv = *(const float4*)(b3 + lg * 4);
    f32x4 acc = {bv.x, bv.y, bv.z, bv.w};
#pragma unroll
    for (int q = 0; q < 2; ++q) {
      const bf16x8 w = *(const bf16x8*)(wpack + ((size_t)(440 + q) * 64 + lane) * 8);
      acc = __builtin_amdgcn_mfma_f32_16x16x32_bf16(w, a[q], acc, 0, 0, 0);
    }
    if (lg < 2) {
      *(f32x4*)(zg + ((size_t)blk * 64 + wv * 16 + l15) * 8 + lg * 4) = acc;
      bf16x4 zv;
#pragma unroll
      for (int r = 0; r < 4; ++r) zv[r] = (__bf16)acc[r];
      *(bf16x4*)(zb + (wv * 16 + l15) * 16 + lg * 8) = zv;
    }
  }
  __syncthreads();

  // ---- E0: 8 -> 128 tanh (K padded to 32, zero weights kill k>=8).
  // z read as bf16x8 rows directly (broadcast across lg). ----
  {
    bf16x8 az[4];
#pragma unroll
    for (int sg = 0; sg < 4; ++sg)
      az[sg] = *(const bf16x8*)(zb + (sg * 16 + l15) * 16);
#pragma unroll
    for (int t = 0; t < 2; ++t) {
      const int nt = wv * 2 + t;
      const float4 bv = *(const float4*)(eb0 + nt * 16 + lg * 4);
      const bf16x8 w = *(const bf16x8*)(wpack + ((size_t)(432 + nt) * 64 + lane) * 8);
#pragma unroll
      for (int sg = 0; sg < 4; ++sg) {
        f32x4 acc = {bv.x, bv.y, bv.z, bv.w};
        acc = __builtin_amdgcn_mfma_f32_16x16x32_bf16(w, az[sg], acc, 0, 0, 0);
        bf16x4 tv;
#pragma unroll
        for (int r = 0; r < 4; ++r) tv[r] = (__bf16)fast_tanh(acc[r]);
        *(bf16x4*)(E0o + (sg * 16 + l15) * 256 + ((nt * 32 + lg * 8) ^ sw)) = tv;
      }
    }
  }
  __syncthreads();

  layer_nks4<1>(E0o, 256, e1, 128, wpack, 416, eb1, lane, wv);    // E1
  __syncthreads();

  // ---- E2 + softmax; sample group = wv ----
  {
    bf16x8 a[2];
#pragma unroll
    for (int q = 0; q < 2; ++q)
      a[q] = *(const bf16x8*)(e1 + (wv * 16 + l15) * 128 + ((q * 64 + lg * 16) ^ sw));
    const float4 bv = *(const float4*)(eb2 + lg * 4);
    f32x4 acc = {bv.x, bv.y, bv.z, bv.w};
#pragma unroll
    for (int q = 0; q < 2; ++q) {
      const bf16x8 w = *(const bf16x8*)(wpack + ((size_t)(442 + q) * 64 + lane) * 8);
      acc = __builtin_amdgcn_mfma_f32_16x16x32_bf16(w, a[q], acc, 0, 0, 0);
    }
    float m = fmaxf(fmaxf(acc[0], acc[1]), fmaxf(acc[2], acc[3]));
    m = fmaxf(m, __shfl_xor(m, 16));
    m = fmaxf(m, __shfl_xor(m, 32));
    float e0v = __expf(acc[0] - m), e1v = __expf(acc[1] - m);
    float e2v = __expf(acc[2] - m), e3v = __expf(acc[3] - m);
    float s = e0v + e1v + e2v + e3v;
    s += __shfl_xor(s, 16);
    s += __shfl_xor(s, 32);
    const float inv = __builtin_amdgcn_rcpf(s);
    float4 g = {e0v * inv, e1v * inv, e2v * inv, e3v * inv};
    *(float4*)(gamma + ((size_t)blk * 64 + wv * 16 + l15) * 16 + lg * 4) = g;
  }
}

// ---------------------------------------------------------------------------
// K2a: moment partials. 1024 blocks x 256 samples each, LDS-staged.
// ---------------------------------------------------------------------------
__global__ __launch_bounds__(256) void k2a_partial(
    const float* __restrict__ zg, const float* __restrict__ gamma,
    float* __restrict__ part)
{
  __shared__ float zl[256 * 8];
  __shared__ float gl[256 * 16];
  __shared__ float red[4][16][46];
  const int tid = threadIdx.x;
  const int blk = blockIdx.x;
  const int s0 = blk * 256;

  {
    const float4 a = *(const float4*)(zg + (size_t)(s0 + tid) * 8);
    const float4 b = *(const float4*)(zg + (size_t)(s0 + tid) * 8 + 4);
    *(float4*)(&zl[tid * 8])     = a;
    *(float4*)(&zl[tid * 8 + 4]) = b;
  }
  {
    const float* gp = gamma + (size_t)(s0 + tid) * 16;
#pragma unroll
    for (int q = 0; q < 4; ++q)
      *(float4*)(&gl[tid * 16 + q * 4]) = *(const float4*)(gp + q * 4);
  }
  __syncthreads();

  const int k = tid & 15, sub = tid >> 4;
  float m2[36], m1[8], gs = 0.f;
#pragma unroll
  for (int i = 0; i < 36; ++i) m2[i] = 0.f;
#pragma unroll
  for (int i = 0; i < 8; ++i) m1[i] = 0.f;

#pragma unroll 4
  for (int i = 0; i < 16; ++i) {
    const int n = i * 16 + sub;
    const float4 za = *(const float4*)(&zl[n * 8]);
    const float4 zb4 = *(const float4*)(&zl[n * 8 + 4]);
    const float zv[8] = {za.x, za.y, za.z, za.w, zb4.x, zb4.y, zb4.z, zb4.w};
    const float g = gl[n * 16 + k];
    gs += g;
    float t[8];
#pragma unroll
    for (int l = 0; l < 8; ++l) { t[l] = g * zv[l]; m1[l] += t[l]; }
    int p = 0;
#pragma unroll
    for (int l = 0; l < 8; ++l)
#pragma unroll
      for (int m = l; m < 8; ++m) {
        m2[p] = fmaf(t[l], zv[m], m2[p]);
        ++p;
      }
  }

#pragma unroll
  for (int i = 0; i < 36; ++i) {
    m2[i] += __shfl_xor(m2[i], 16);
    m2[i] += __shfl_xor(m2[i], 32);
  }
#pragma unroll
  for (int i = 0; i < 8; ++i) {
    m1[i] += __shfl_xor(m1[i], 16);
    m1[i] += __shfl_xor(m1[i], 32);
  }
  gs += __shfl_xor(gs, 16);
  gs += __shfl_xor(gs, 32);

  const int lane = tid & 63, wv = tid >> 6;
  if (lane < 16) {
#pragma unroll
    for (int i = 0; i < 36; ++i) red[wv][lane][i] = m2[i];
#pragma unroll
    for (int i = 0; i < 8; ++i) red[wv][lane][36 + i] = m1[i];
    red[wv][lane][44] = gs;
  }
  __syncthreads();

  for (int o = tid; o < 768; o += 256) {
    const int kk = o / 48, p = o % 48;
    float v = 0.f;
    if (p < 45)
      v = red[0][kk][p] + red[1][kk][p] + red[2][kk][p] + red[3][kk][p];
    part[(size_t)blk * 768 + o] = v;
  }
}

// ---------------------------------------------------------------------------
// K2b: reduce part[1024][768] -> stats[768]. 24 blocks.
// ---------------------------------------------------------------------------
__global__ __launch_bounds__(256) void k2b_reduce(
    const float* __restrict__ part, float* __restrict__ stats)
{
  const int oi = blockIdx.x % 3, jc = blockIdx.x / 3;
  const int o = oi * 256 + threadIdx.x;
  float s = 0.f;
#pragma unroll 4
  for (int j = jc * 128; j < jc * 128 + 128; ++j)
    s += part[(size_t)j * 768 + o];
  atomicAdd(&stats[o], s);
}

// ---------------------------------------------------------------------------
// K3: finalize GMM params -> quadratic coefficients (stats stride 48)
// ---------------------------------------------------------------------------
__global__ void k3_finalize(const float* __restrict__ stats, float* __restrict__ coef)
{
  const int k = threadIdx.x;
  if (k >= 16) return;
  const float* sk = stats + k * 48;
  const float gs = sk[44];
  float mu[8];
#pragma unroll
  for (int l = 0; l < 8; ++l) mu[l] = sk[36 + l] / gs;

  float S[8][8];
  {
    int p = 0;
    for (int l = 0; l < 8; ++l)
      for (int m = l; m < 8; ++m) {
        const float v = sk[p++] / gs - mu[l] * mu[m];
        S[l][m] = v; S[m][l] = v;
      }
  }
  for (int l = 0; l < 8; ++l) S[l][l] += 1e-6f;

  float L[8][8];
  for (int i = 0; i < 8; ++i)
    for (int j = 0; j <= i; ++j) {
      float s = S[i][j];
      for (int t = 0; t < j; ++t) s -= L[i][t] * L[j][t];
      if (i == j) L[i][i] = sqrtf(s);
      else        L[i][j] = s / L[j][j];
    }
  float logdet = 0.f;
  for (int i = 0; i < 8; ++i) logdet += logf(L[i][i]);
  logdet *= 2.f;

  float U[8][8];
  for (int j = 0; j < 8; ++j) {
    U[j][j] = 1.f / L[j][j];
    for (int i = j + 1; i < 8; ++i) {
      float s = 0.f;
      for (int t = j; t < i; ++t) s += L[i][t] * U[t][j];
      U[i][j] = -s / L[i][i];
    }
  }
  float Amat[8][8];
  for (int l = 0; l < 8; ++l)
    for (int m = l; m < 8; ++m) {
      float s = 0.f;
      for (int i = m; i < 8; ++i) s += U[i][l] * U[i][m];
      Amat[l][m] = s; Amat[m][l] = s;
    }
  float c[8];
  for (int l = 0; l < 8; ++l) {
    float s = 0.f;
    for (int m = 0; m < 8; ++m) s += Amat[l][m] * mu[m];
    c[l] = s;
  }
  float muAmu = 0.f;
  for (int l = 0; l < 8; ++l) muAmu += c[l] * mu[l];

  const float LOG2PI = 1.8378770664093453f;
  const float cnst = logf(gs) - logf((float)NSAMP)
                   - 0.5f * (8.f * LOG2PI + logdet + muAmu);

  float* ck = coef + k * 48;
  {
    int p = 0;
    for (int l = 0; l < 8; ++l)
      for (int m = l; m < 8; ++m) {
        ck[p] = (l == m) ? (-0.5f * Amat[l][l]) : (-Amat[l][m]);
        ++p;
      }
  }
  for (int l = 0; l < 8; ++l) ck[36 + l] = c[l];
  ck[44] = cnst;
  ck[45] = 0.f; ck[46] = 0.f; ck[47] = 0.f;
}

// ---------------------------------------------------------------------------
// K4: per-sample energy + online LSE
// ---------------------------------------------------------------------------
__global__ __launch_bounds__(256) void k4_energy(
    const float* __restrict__ zg, const float* __restrict__ coef,
    float* __restrict__ prob)
{
  __shared__ float C[16 * 48];
  for (int i = threadIdx.x; i < 16 * 48; i += 256) C[i] = coef[i];
  __syncthreads();

  const int n = blockIdx.x * 256 + threadIdx.x;
  const float4 za = *(const float4*)(zg + (size_t)n * 8);
  const float4 zb = *(const float4*)(zg + (size_t)n * 8 + 4);
  const float z[8] = {za.x, za.y, za.z, za.w, zb.x, zb.y, zb.z, zb.w};

  float pr[36];
  {
    int p = 0;
#pragma unroll
    for (int l = 0; l < 8; ++l)
#pragma unroll
      for (int m = l; m < 8; ++m) pr[p++] = z[l] * z[m];
  }

  float mx = -1e30f, sm = 0.f;
#pragma unroll
  for (int k = 0; k < 16; ++k) {
    const float4* c4 = (const float4*)&C[k * 48];
    float acc = C[k * 48 + 44];
#pragma unroll
    for (int q = 0; q < 9; ++q) {
      const float4 t = c4[q];
      acc = fmaf(t.x, pr[q * 4 + 0], acc);
      acc = fmaf(t.y, pr[q * 4 + 1], acc);
      acc = fmaf(t.z, pr[q * 4 + 2], acc);
      acc = fmaf(t.w, pr[q * 4 + 3], acc);
    }
    {
      const float4 t = c4[9];
      acc = fmaf(t.x, z[0], acc); acc = fmaf(t.y, z[1], acc);
      acc = fmaf(t.z, z[2], acc); acc = fmaf(t.w, z[3], acc);
    }
    {
      const float4 t = c4[10];
      acc = fmaf(t.x, z[4], acc); acc = fmaf(t.y, z[5], acc);
      acc = fmaf(t.z, z[6], acc); acc = fmaf(t.w, z[7], acc);
    }
    const float nm = fmaxf(mx, acc);
    sm = sm * __expf(mx - nm) + __expf(acc - nm);
    mx = nm;
  }
  prob[n] = -(mx + __logf(sm));
}

// ---------------------------------------------------------------------------
extern "C" void kernel_launch(void* const* d_in, const int* in_sizes, int n_in,
                              void* d_out, int out_size, void* d_ws, size_t ws_size,
                              hipStream_t stream)
{
  const float* x   = (const float*)d_in[0];
  const float* W0  = (const float*)d_in[1];
  const float* b0  = (const float*)d_in[2];
  const float* W1  = (const float*)d_in[3];
  const float* b1  = (const float*)d_in[4];
  const float* W2  = (const float*)d_in[5];
  const float* b2  = (const float*)d_in[6];
  const float* W3  = (const float*)d_in[7];
  const float* b3  = (const float*)d_in[8];
  const float* E0w = (const float*)d_in[9];
  const float* eb0 = (const float*)d_in[10];
  const float* E1w = (const float*)d_in[11];
  const float* eb1 = (const float*)d_in[12];
  const float* E2w = (const float*)d_in[13];
  const float* eb2 = (const float*)d_in[14];

  float* out  = (float*)d_out;
  float* prob = out;              // [N]
  float* zg   = out + NSAMP;      // [N][8]

  // ws: wpack (444 frags * 512 B, padded to 448 KB) | gamma [N][16]
  //   | stats 768 | coef 768 | part [1024][768]
  unsigned short* wpack = (unsigned short*)d_ws;
  float* ws    = (float*)d_ws;
  float* gamma = ws + 114688;
  float* stats = gamma + (size_t)NSAMP * 16;
  float* coef  = stats + 768;
  float* part  = coef + 768;

  hipMemsetAsync(stats, 0, 768 * sizeof(float), stream);

  k0_pack<<<444, 64, 0, stream>>>(W0, W1, W2, E1w, E0w, W3, E2w, wpack);
  k1_mfma<<<NSAMP / TMS, 256, 0, stream>>>(x, wpack, b0, b1, b2, b3,
                                           eb0, eb1, eb2, zg, gamma);
  k2a_partial<<<1024, 256, 0, stream>>>(zg, gamma, part);
  k2b_reduce<<<24, 256, 0, stream>>>(part, stats);
  k3_finalize<<<1, 64, 0, stream>>>(stats, coef);
  k4_energy<<<NSAMP / 256, 256, 0, stream>>>(zg, coef, prob);
}